// Round 5
// baseline (5639.231 us; speedup 1.0000x reference)
//
#include <hip/hip_runtime.h>

#define D 64
constexpr int U_ = 50000, B_ = 20000, I_ = 40000;
constexpr int RPB  = 128;        // rows per bucket (LDS tile = 128*64 floats = 32 KB)
constexpr int MAXB = 708;        // max buckets (n<=90000 -> 704)
constexpr int EPT  = 16;         // edges per thread in hist/partition
constexpr int TILE = 256 * EPT;  // 4096 edges per block

// ---- degree histogram (random 4B atomics, L2-resident) + bucket counts ----
__global__ void k_hist(const int* __restrict__ rows, int nnz,
                       int* __restrict__ cnt, int* __restrict__ bcnt, int nbuck) {
    __shared__ int lb[MAXB];
    for (int i = threadIdx.x; i < nbuck; i += 256) lb[i] = 0;
    __syncthreads();
    int e0 = blockIdx.x * TILE + threadIdx.x;
    for (int k = 0; k < EPT; k++) {
        int e = e0 + k * 256;
        if (e < nnz) {
            int r = rows[e];
            atomicAdd(&cnt[r], 1);
            atomicAdd(&lb[r >> 7], 1);
        }
    }
    __syncthreads();
    for (int i = threadIdx.x; i < nbuck; i += 256)
        if (lb[i]) atomicAdd(&bcnt[i], lb[i]);
}

// Degree -> scale. mode 0: 1/(sqrt(deg)+1e-8)  mode 1: 1/max(deg,1)
__global__ void k_scale(const int* __restrict__ cnt, int n,
                        float* __restrict__ scale, int mode) {
    int i = blockIdx.x * blockDim.x + threadIdx.x;
    if (i >= n) return;
    int c = cnt[i];
    scale[i] = (mode == 0) ? 1.0f / (sqrtf((float)c) + 1e-8f)
                           : 1.0f / (float)max(c, 1);
}

// ---- bucket-count exclusive scan (<=704 entries, one block) ----
__global__ void k_bscan(const int* __restrict__ bcnt, int nbuck,
                        int* __restrict__ bktbase, int* __restrict__ bktcur) {
    __shared__ int sm[1024];
    int t = threadIdx.x;
    sm[t] = (t < nbuck) ? bcnt[t] : 0;
    __syncthreads();
    for (int off = 1; off < 1024; off <<= 1) {
        int v = (t >= off) ? sm[t - off] : 0;
        __syncthreads();
        sm[t] += v;
        __syncthreads();
    }
    if (t < nbuck) { int ex = t ? sm[t - 1] : 0; bktbase[t] = ex; bktcur[t] = ex; }
    if (t == 0) bktbase[nbuck] = sm[1023];
}

// ---- bucket partition: write (packed(rowlocal,col), val) pairs, grouped ----
// Coalesced-run writes (~bucket runs of ~180B) instead of random 4B scatter.
__global__ void k_part(const int* __restrict__ rows, const int* __restrict__ cols,
                       int nnz, int nbuck, const float* __restrict__ scale, int mode,
                       int* __restrict__ bktcur, int2* __restrict__ ep) {
    __shared__ int lcnt[MAXB], lbase[MAXB];
    int er[EPT], ec[EPT];
    int t = threadIdx.x;
    for (int i = t; i < nbuck; i += 256) lcnt[i] = 0;
    __syncthreads();
    int e0 = blockIdx.x * TILE + t;
    for (int k = 0; k < EPT; k++) {
        int e = e0 + k * 256;
        if (e < nnz) {
            er[k] = rows[e];
            ec[k] = cols[e];
            atomicAdd(&lcnt[er[k] >> 7], 1);
        } else er[k] = -1;
    }
    __syncthreads();
    for (int b = t; b < nbuck; b += 256) {
        int c = lcnt[b];
        lbase[b] = c ? atomicAdd(&bktcur[b], c) : 0;
        lcnt[b] = 0;
    }
    __syncthreads();
    for (int k = 0; k < EPT; k++) {
        if (er[k] < 0) continue;
        int b = er[k] >> 7;
        int pos = lbase[b] + atomicAdd(&lcnt[b], 1);
        float v = mode ? 1.0f : scale[ec[k]];       // col factor baked into edge
        int packed = ((er[k] & (RPB - 1)) << 17) | ec[k];   // col < 2^17
        ep[pos] = make_int2(packed, __float_as_int(v));
    }
}

// ---- bucket-LDS SpMM + scale + l2norm + acc, one block per bucket ----
// flags: 1=write fout, 2=acc init (=raw+r), 4=l2norm, 8=do acc
__global__ void __launch_bounds__(256)
k_layer(const int2* __restrict__ ep, const int* __restrict__ bktbase,
        int n, int nsplit,
        const float* __restrict__ xA, const float* __restrict__ xB_adj,
        const float* __restrict__ scale, float inv,
        float* __restrict__ fout, int flags,
        float* __restrict__ accA, float* __restrict__ accB) {
    __shared__ float ly[RPB * D];
    int t = threadIdx.x, lane = t & 63, wid = t >> 6;
    for (int i = t; i < RPB * D; i += 256) ly[i] = 0.f;
    __syncthreads();
    int s = bktbase[blockIdx.x], e = bktbase[blockIdx.x + 1];
    for (int base = s + wid * 64; base < e; base += 256) {
        int li = base + lane;
        int2 pk = (li < e) ? ep[li] : make_int2(0, 0);
        int   pj = pk.x;
        float vj = __int_as_float(pk.y);
        int jn = e - base; if (jn > 64) jn = 64;
        for (int j = 0; j < jn; j++) {
            int   p = __shfl(pj, j, 64);
            float v = __shfl(vj, j, 64);
            int c  = p & 0x1FFFF;
            int rl = p >> 17;
            const float* xp = (c < nsplit) ? xA : xB_adj;   // wave-uniform
            atomicAdd(&ly[rl * D + lane], v * xp[(size_t)c * D + lane]);
        }
    }
    __syncthreads();
    int r0 = blockIdx.x * RPB;
    for (int rl = wid; rl < RPB; rl += 4) {
        int row = r0 + rl;
        if (row >= n) break;
        float v = ly[rl * D + lane] * scale[row] * inv;
        if (flags & 1) fout[(size_t)row * D + lane] = v;
        float r = v;
        if (flags & 4) {
            float sq = v * v;
            #pragma unroll
            for (int off = 32; off; off >>= 1) sq += __shfl_xor(sq, off, 64);
            r = v / fmaxf(sqrtf(sq), 1e-12f);
        }
        if (flags & 8) {
            float* p = (row < U_) ? &accA[(size_t)row * D + lane]
                                  : &accB[(size_t)(row - U_) * D + lane];
            if (flags & 2) {
                const float* xr = (row < nsplit) ? xA : xB_adj;
                *p = xr[(size_t)row * D + lane] + r;
            } else *p += r;
        }
    }
}

extern "C" void kernel_launch(void* const* d_in, const int* in_sizes, int n_in,
                              void* d_out, int out_size, void* d_ws, size_t ws_size,
                              hipStream_t stream) {
    const float* users   = (const float*)d_in[0];
    const float* bundles = (const float*)d_in[1];
    const float* items   = (const float*)d_in[2];
    const int*   ui_idx  = (const int*)d_in[3];
    const int*   ub_idx  = (const int*)d_in[5];
    const int*   ubx_idx = (const int*)d_in[7];
    const int*   agg_idx = (const int*)d_in[9];
    const int ui_nnz  = in_sizes[4];
    const int ub_nnz  = in_sizes[6];
    const int ubx_nnz = in_sizes[8];
    const int agg_nnz = in_sizes[10];

    float* out = (float*)d_out;
    const size_t rowf = (size_t)D;

    // ---- workspace carve-up ----
    const size_t NMAX   = (size_t)(U_ + I_) * D;      // 5.76M floats
    const int    NNZMAX = 2000000;                    // ui graph (largest)
    const int    NROWMX = U_ + I_ + 1;
    float* gbuf    = (float*)d_ws;                    // 23.04 MB (layer-0 out)
    float* acc_itm = gbuf + NMAX;                     // 10.24 MB
    float* scale   = acc_itm + (size_t)I_ * D;        //  0.36 MB
    int2*  ep      = (int2*)(scale + NROWMX);         // 16.0 MB packed edges
    int*   cnt     = (int*)(ep + NNZMAX);             //  0.36 MB
    int*   bcnt    = cnt + NROWMX;                    //  ~3 KB
    int*   bktbase = bcnt + MAXB;
    int*   bktcur  = bktbase + MAXB + 1;

    // ---- output layout ----
    float* out_IL_u = out;
    float* out_BL_u = out + (size_t)U_ * rowf;
    float* out_XL_u = out + (size_t)2 * U_ * rowf;
    float* out_IL_b = out + (size_t)3 * U_ * rowf;
    float* out_BL_b = out + (size_t)3 * U_ * rowf + (size_t)B_ * rowf;
    float* out_XL_b = out + (size_t)3 * U_ * rowf + (size_t)2 * B_ * rowf;

    auto build = [&](const int* idxp, int nnz, int n, int mode) -> int {
        int nbuck = (n + RPB - 1) / RPB;
        int G = (nnz + TILE - 1) / TILE;
        hipMemsetAsync(cnt, 0, (size_t)n * sizeof(int), stream);
        hipMemsetAsync(bcnt, 0, (size_t)nbuck * sizeof(int), stream);
        hipLaunchKernelGGL(k_hist, dim3(G), dim3(256), 0, stream,
                           idxp, nnz, cnt, bcnt, nbuck);
        hipLaunchKernelGGL(k_scale, dim3((n + 255) / 256), dim3(256), 0, stream,
                           cnt, n, scale, mode);
        hipLaunchKernelGGL(k_bscan, dim3(1), dim3(1024), 0, stream,
                           bcnt, nbuck, bktbase, bktcur);
        hipLaunchKernelGGL(k_part, dim3(G), dim3(256), 0, stream,
                           idxp, idxp + nnz, nnz, nbuck, scale, mode, bktcur, ep);
        return nbuck;
    };

    auto propagate = [&](const int* idxp, int nnz,
                         const float* Bfeat, int nB, float* accA, float* accB) {
        const int n = U_ + nB;
        int nbuck = build(idxp, nnz, n, 0);
        // layer 0: g = spmm(raw)/2 ; acc = raw + l2norm(g)
        hipLaunchKernelGGL(k_layer, dim3(nbuck), dim3(256), 0, stream,
                           ep, bktbase, n, U_,
                           users, Bfeat - (size_t)U_ * rowf, scale,
                           0.5f, gbuf, 1 | 2 | 4 | 8, accA, accB);
        // layer 1: f = spmm(g)/3 ; acc += l2norm(f)   (f never read -> no write)
        hipLaunchKernelGGL(k_layer, dim3(nbuck), dim3(256), 0, stream,
                           ep, bktbase, n, n,
                           gbuf, gbuf, scale,
                           1.0f / 3.0f, (float*)nullptr, 4 | 8, accA, accB);
    };

    // item-level propagation over user-item graph
    propagate(ui_idx, ui_nnz, items, I_, out_IL_u, acc_itm);

    // bundle aggregation: IL_b = agg @ IL_i  (row-normalized; write-only epilogue)
    {
        int nbuck = build(agg_idx, agg_nnz, B_, 1);
        hipLaunchKernelGGL(k_layer, dim3(nbuck), dim3(256), 0, stream,
                           ep, bktbase, B_, I_,
                           acc_itm, acc_itm, scale,
                           1.0f, out_IL_b, 1, (float*)nullptr, (float*)nullptr);
    }

    // bundle-level propagation over user-bundle graph
    propagate(ub_idx, ub_nnz, bundles, B_, out_BL_u, out_BL_b);

    // ingredient-augmented user-bundle propagation
    propagate(ubx_idx, ubx_nnz, bundles, B_, out_XL_u, out_XL_b);
}

// Round 6
// 1039.754 us; speedup vs baseline: 5.4236x; 5.4236x over previous
//
#include <hip/hip_runtime.h>

#define D 64
constexpr int U_ = 50000, B_ = 20000, I_ = 40000;
constexpr int RPB  = 128;        // rows per bucket
constexpr int MAXB = 708;        // max buckets (n<=90000 -> 704)
constexpr int TILE = 8192;       // edges per partition block

// ---- bucket histogram (LDS-aggregated; no random global atomics) ----
__global__ void k_histb(const int* __restrict__ rows, int nnz,
                        int* __restrict__ bcnt, int nbuck) {
    __shared__ int lb[MAXB];
    for (int i = threadIdx.x; i < nbuck; i += 256) lb[i] = 0;
    __syncthreads();
    int e0 = blockIdx.x * TILE, e1 = min(e0 + TILE, nnz);
    for (int e = e0 + threadIdx.x; e < e1; e += 256)
        atomicAdd(&lb[rows[e] >> 7], 1);
    __syncthreads();
    for (int i = threadIdx.x; i < nbuck; i += 256)
        if (lb[i]) atomicAdd(&bcnt[i], lb[i]);
}

// ---- bucket-count exclusive scan (<=704 entries, one block) ----
__global__ void k_bscan(const int* __restrict__ bcnt, int nbuck,
                        int* __restrict__ bktbase, int* __restrict__ bktcur) {
    __shared__ int sm[1024];
    int t = threadIdx.x;
    sm[t] = (t < nbuck) ? bcnt[t] : 0;
    __syncthreads();
    for (int off = 1; off < 1024; off <<= 1) {
        int v = (t >= off) ? sm[t - off] : 0;
        __syncthreads();
        sm[t] += v;
        __syncthreads();
    }
    if (t < nbuck) { int ex = t ? sm[t - 1] : 0; bktbase[t] = ex; bktcur[t] = ex; }
    if (t == 0) bktbase[nbuck] = sm[1023];
}

// ---- partition edges into bucket-grouped order (packed 4B entries) ----
__global__ void __launch_bounds__(256)
k_part(const int* __restrict__ rows, const int* __restrict__ cols,
       int nnz, int nbuck, int* __restrict__ bktcur, int* __restrict__ ep) {
    __shared__ int lcnt[MAXB], lbase[MAXB];
    int t = threadIdx.x;
    for (int i = t; i < nbuck; i += 256) lcnt[i] = 0;
    __syncthreads();
    int e0 = blockIdx.x * TILE, e1 = min(e0 + TILE, nnz);
    for (int e = e0 + t; e < e1; e += 256)
        atomicAdd(&lcnt[rows[e] >> 7], 1);
    __syncthreads();
    for (int b = t; b < nbuck; b += 256) {
        int c = lcnt[b];
        lbase[b] = c ? atomicAdd(&bktcur[b], c) : 0;
        lcnt[b] = 0;
    }
    __syncthreads();
    for (int e = e0 + t; e < e1; e += 256) {
        int r = rows[e], c = cols[e];
        int b = r >> 7;
        int pos = lbase[b] + atomicAdd(&lcnt[b], 1);
        ep[pos] = ((r & (RPB - 1)) << 17) | c;    // col < 2^17
    }
}

// ---- per-bucket counting sort -> row-exact CSR; emits rowstart & scale ----
// Random writes confined to the bucket's own ~11KB region (single block).
__global__ void __launch_bounds__(256)
k_sort(const int* __restrict__ ep, const int* __restrict__ bktbase,
       int n, int mode, int* __restrict__ ecolS,
       int* __restrict__ rowstart, float* __restrict__ scale) {
    __shared__ int lcnt[RPB], lpre[RPB];
    int t = threadIdx.x;
    if (t < RPB) lcnt[t] = 0;
    __syncthreads();
    int s = bktbase[blockIdx.x], e = bktbase[blockIdx.x + 1];
    for (int i = s + t; i < e; i += 256)
        atomicAdd(&lcnt[ep[i] >> 17], 1);
    __syncthreads();
    if (t < RPB) lpre[t] = lcnt[t];
    __syncthreads();
    for (int off = 1; off < RPB; off <<= 1) {      // Hillis-Steele inclusive
        int v = 0;
        if (t < RPB && t >= off) v = lpre[t - off];
        __syncthreads();
        if (t < RPB) lpre[t] += v;
        __syncthreads();
    }
    int r0 = blockIdx.x * RPB;
    if (t < RPB) {
        int row = r0 + t;
        if (row < n) {
            int ex = t ? lpre[t - 1] : 0;
            rowstart[row] = s + ex;
            int c = lcnt[t];
            scale[row] = (mode == 0) ? 1.0f / (sqrtf((float)c) + 1e-8f)
                                     : 1.0f / (float)max(c, 1);
            lcnt[t] = s + ex;                      // reuse as write cursor
        } else lcnt[t] = 0;
    }
    if (blockIdx.x == gridDim.x - 1 && t == 0) rowstart[n] = e;
    __syncthreads();
    for (int i = s + t; i < e; i += 256) {
        int p = ep[i];
        int pos = atomicAdd(&lcnt[p >> 17], 1);
        ecolS[pos] = p & 0x1FFFF;
    }
}

// ---- fused CSR-SpMM + scale + l2norm + acc (round-4 proven version) ----
__global__ void k_layer(const int* __restrict__ rowstart, const int* __restrict__ ecol,
                        const float* __restrict__ scale, int n, int nsplit,
                        const float* __restrict__ xA, const float* __restrict__ xB_adj,
                        float inv, float* __restrict__ fout, int write_f, int init,
                        float* __restrict__ accA, float* __restrict__ accB) {
    int row = (blockIdx.x << 2) + (threadIdx.x >> 6);
    if (row >= n) return;
    int lane = threadIdx.x & 63;
    int s = rowstart[row], e = rowstart[row + 1];
    float acc = 0.f;
    for (int base = s; base < e; base += 64) {
        int jn = e - base; if (jn > 64) jn = 64;
        int li = base + (lane < jn ? lane : jn - 1);   // clamped vector load
        int   cj = ecol[li];
        float vj = scale[cj];                          // L2-resident table gather
        for (int j = 0; j < jn; j++) {
            int   c = __shfl(cj, j, 64);
            float v = __shfl(vj, j, 64);
            const float* xp = (c < nsplit) ? xA : xB_adj;   // wave-uniform select
            acc += v * xp[(size_t)c * D + lane];
        }
    }
    float v = acc * scale[row] * inv;
    if (write_f) fout[(size_t)row * D + lane] = v;
    float sq = v * v;
    #pragma unroll
    for (int off = 32; off; off >>= 1) sq += __shfl_xor(sq, off, 64);
    float r = v / fmaxf(sqrtf(sq), 1e-12f);
    if (row < U_) {
        float* p = &accA[(size_t)row * D + lane];
        if (init) { const float* xr = (row < nsplit) ? xA : xB_adj;
                    *p = xr[(size_t)row * D + lane] + r; }
        else      *p += r;
    } else {
        float* p = &accB[(size_t)(row - U_) * D + lane];
        if (init) { const float* xr = (row < nsplit) ? xA : xB_adj;
                    *p = xr[(size_t)row * D + lane] + r; }
        else      *p += r;
    }
}

// Plain CSR-SpMM with row scaling (bundle aggregation): y[r] = rs[r]*sum x[c]
__global__ void k_spmm_csr(const int* __restrict__ rowstart, const int* __restrict__ ecol,
                           const float* __restrict__ rs, int n,
                           const float* __restrict__ x, float* __restrict__ y) {
    int row = (blockIdx.x << 2) + (threadIdx.x >> 6);
    if (row >= n) return;
    int lane = threadIdx.x & 63;
    int s = rowstart[row], e = rowstart[row + 1];
    float acc = 0.f;
    for (int base = s; base < e; base += 64) {
        int jn = e - base; if (jn > 64) jn = 64;
        int li = base + (lane < jn ? lane : jn - 1);
        int cj = ecol[li];
        for (int j = 0; j < jn; j++) {
            int c = __shfl(cj, j, 64);
            acc += x[(size_t)c * D + lane];
        }
    }
    y[(size_t)row * D + lane] = acc * rs[row];
}

extern "C" void kernel_launch(void* const* d_in, const int* in_sizes, int n_in,
                              void* d_out, int out_size, void* d_ws, size_t ws_size,
                              hipStream_t stream) {
    const float* users   = (const float*)d_in[0];
    const float* bundles = (const float*)d_in[1];
    const float* items   = (const float*)d_in[2];
    const int*   ui_idx  = (const int*)d_in[3];
    const int*   ub_idx  = (const int*)d_in[5];
    const int*   ubx_idx = (const int*)d_in[7];
    const int*   agg_idx = (const int*)d_in[9];
    const int ui_nnz  = in_sizes[4];
    const int ub_nnz  = in_sizes[6];
    const int ubx_nnz = in_sizes[8];
    const int agg_nnz = in_sizes[10];

    float* out = (float*)d_out;
    const size_t rowf = (size_t)D;

    // ---- workspace carve-up ----
    const size_t NMAX   = (size_t)(U_ + I_) * D;      // 5.76M floats
    const int    NNZMAX = 2000000;                    // ui graph (largest)
    const int    NROWMX = U_ + I_ + 1;
    float* gbuf    = (float*)d_ws;                    // 23.04 MB (layer-0 out)
    float* acc_itm = gbuf + NMAX;                     // 10.24 MB
    float* scale   = acc_itm + (size_t)I_ * D;        //  0.36 MB
    int*   ep      = (int*)(scale + NROWMX);          //  8.0 MB bucket-grouped
    int*   ecolS   = ep + NNZMAX;                     //  8.0 MB row-sorted cols
    int*   rowstart= ecolS + NNZMAX;                  //  0.36 MB
    int*   bcnt    = rowstart + NROWMX;               //  ~3 KB
    int*   bktbase = bcnt + MAXB;
    int*   bktcur  = bktbase + MAXB + 1;

    // ---- output layout ----
    float* out_IL_u = out;
    float* out_BL_u = out + (size_t)U_ * rowf;
    float* out_XL_u = out + (size_t)2 * U_ * rowf;
    float* out_IL_b = out + (size_t)3 * U_ * rowf;
    float* out_BL_b = out + (size_t)3 * U_ * rowf + (size_t)B_ * rowf;
    float* out_XL_b = out + (size_t)3 * U_ * rowf + (size_t)2 * B_ * rowf;

    auto build = [&](const int* idxp, int nnz, int n, int mode) {
        int nbuck = (n + RPB - 1) / RPB;
        int G = (nnz + TILE - 1) / TILE;
        hipMemsetAsync(bcnt, 0, (size_t)nbuck * sizeof(int), stream);
        hipLaunchKernelGGL(k_histb, dim3(G), dim3(256), 0, stream,
                           idxp, nnz, bcnt, nbuck);
        hipLaunchKernelGGL(k_bscan, dim3(1), dim3(1024), 0, stream,
                           bcnt, nbuck, bktbase, bktcur);
        hipLaunchKernelGGL(k_part, dim3(G), dim3(256), 0, stream,
                           idxp, idxp + nnz, nnz, nbuck, bktcur, ep);
        hipLaunchKernelGGL(k_sort, dim3(nbuck), dim3(256), 0, stream,
                           ep, bktbase, n, mode, ecolS, rowstart, scale);
    };

    auto propagate = [&](const int* idxp, int nnz,
                         const float* Bfeat, int nB, float* accA, float* accB) {
        const int n = U_ + nB;
        build(idxp, nnz, n, 0);
        // layer 0: g = spmm(raw)/2 ; acc = raw + l2norm(g)
        hipLaunchKernelGGL(k_layer, dim3((n + 3) / 4), dim3(256), 0, stream,
                           rowstart, ecolS, scale, n, U_,
                           users, Bfeat - (size_t)U_ * rowf,
                           0.5f, gbuf, 1, 1, accA, accB);
        // layer 1: f = spmm(g)/3 ; acc += l2norm(f)   (f never read -> no write)
        hipLaunchKernelGGL(k_layer, dim3((n + 3) / 4), dim3(256), 0, stream,
                           rowstart, ecolS, scale, n, n,
                           gbuf, gbuf,
                           1.0f / 3.0f, (float*)nullptr, 0, 0, accA, accB);
    };

    // item-level propagation over user-item graph
    propagate(ui_idx, ui_nnz, items, I_, out_IL_u, acc_itm);

    // bundle aggregation: IL_b = agg @ IL_i   (row-normalized)
    build(agg_idx, agg_nnz, B_, 1);
    hipLaunchKernelGGL(k_spmm_csr, dim3((B_ + 3) / 4), dim3(256), 0, stream,
                       rowstart, ecolS, scale, B_, acc_itm, out_IL_b);

    // bundle-level propagation over user-bundle graph
    propagate(ub_idx, ub_nnz, bundles, B_, out_BL_u, out_BL_b);

    // ingredient-augmented user-bundle propagation
    propagate(ubx_idx, ubx_nnz, bundles, B_, out_XL_u, out_XL_b);
}

// Round 7
// 1036.886 us; speedup vs baseline: 5.4386x; 1.0028x over previous
//
#include <hip/hip_runtime.h>

#define D 64
constexpr int U_ = 50000, B_ = 20000, I_ = 40000;
constexpr int RPB  = 128;        // rows per bucket
constexpr int MAXB = 708;        // max buckets (n<=90000 -> 704)
constexpr int TILE = 8192;       // edges per partition block

// ---- bucket histogram (LDS-aggregated; no random global atomics) ----
__global__ void k_histb(const int* __restrict__ rows, int nnz,
                        int* __restrict__ bcnt, int nbuck) {
    __shared__ int lb[MAXB];
    for (int i = threadIdx.x; i < nbuck; i += 256) lb[i] = 0;
    __syncthreads();
    int e0 = blockIdx.x * TILE, e1 = min(e0 + TILE, nnz);
    for (int e = e0 + threadIdx.x; e < e1; e += 256)
        atomicAdd(&lb[rows[e] >> 7], 1);
    __syncthreads();
    for (int i = threadIdx.x; i < nbuck; i += 256)
        if (lb[i]) atomicAdd(&bcnt[i], lb[i]);
}

// ---- bucket-count exclusive scan (<=704 entries, one block) ----
__global__ void k_bscan(const int* __restrict__ bcnt, int nbuck,
                        int* __restrict__ bktbase, int* __restrict__ bktcur) {
    __shared__ int sm[1024];
    int t = threadIdx.x;
    sm[t] = (t < nbuck) ? bcnt[t] : 0;
    __syncthreads();
    for (int off = 1; off < 1024; off <<= 1) {
        int v = (t >= off) ? sm[t - off] : 0;
        __syncthreads();
        sm[t] += v;
        __syncthreads();
    }
    if (t < nbuck) { int ex = t ? sm[t - 1] : 0; bktbase[t] = ex; bktcur[t] = ex; }
    if (t == 0) bktbase[nbuck] = sm[1023];
}

// ---- partition edges into bucket-grouped order (packed 4B entries) ----
__global__ void __launch_bounds__(256)
k_part(const int* __restrict__ rows, const int* __restrict__ cols,
       int nnz, int nbuck, int* __restrict__ bktcur, int* __restrict__ ep) {
    __shared__ int lcnt[MAXB], lbase[MAXB];
    int t = threadIdx.x;
    for (int i = t; i < nbuck; i += 256) lcnt[i] = 0;
    __syncthreads();
    int e0 = blockIdx.x * TILE, e1 = min(e0 + TILE, nnz);
    for (int e = e0 + t; e < e1; e += 256)
        atomicAdd(&lcnt[rows[e] >> 7], 1);
    __syncthreads();
    for (int b = t; b < nbuck; b += 256) {
        int c = lcnt[b];
        lbase[b] = c ? atomicAdd(&bktcur[b], c) : 0;
        lcnt[b] = 0;
    }
    __syncthreads();
    for (int e = e0 + t; e < e1; e += 256) {
        int r = rows[e], c = cols[e];
        int b = r >> 7;
        int pos = lbase[b] + atomicAdd(&lcnt[b], 1);
        ep[pos] = ((r & (RPB - 1)) << 17) | c;    // col < 2^17
    }
}

// ---- per-bucket counting sort -> row-exact CSR; emits rowstart & scale ----
__global__ void __launch_bounds__(256)
k_sort(const int* __restrict__ ep, const int* __restrict__ bktbase,
       int n, int mode, int* __restrict__ ecolS,
       int* __restrict__ rowstart, float* __restrict__ scale) {
    __shared__ int lcnt[RPB], lpre[RPB];
    int t = threadIdx.x;
    if (t < RPB) lcnt[t] = 0;
    __syncthreads();
    int s = bktbase[blockIdx.x], e = bktbase[blockIdx.x + 1];
    for (int i = s + t; i < e; i += 256)
        atomicAdd(&lcnt[ep[i] >> 17], 1);
    __syncthreads();
    if (t < RPB) lpre[t] = lcnt[t];
    __syncthreads();
    for (int off = 1; off < RPB; off <<= 1) {      // Hillis-Steele inclusive
        int v = 0;
        if (t < RPB && t >= off) v = lpre[t - off];
        __syncthreads();
        if (t < RPB) lpre[t] += v;
        __syncthreads();
    }
    int r0 = blockIdx.x * RPB;
    if (t < RPB) {
        int row = r0 + t;
        if (row < n) {
            int ex = t ? lpre[t - 1] : 0;
            rowstart[row] = s + ex;
            int c = lcnt[t];
            scale[row] = (mode == 0) ? 1.0f / (sqrtf((float)c) + 1e-8f)
                                     : 1.0f / (float)max(c, 1);
            lcnt[t] = s + ex;                      // reuse as write cursor
        } else lcnt[t] = 0;
    }
    if (blockIdx.x == gridDim.x - 1 && t == 0) rowstart[n] = e;
    __syncthreads();
    for (int i = s + t; i < e; i += 256) {
        int p = ep[i];
        int pos = atomicAdd(&lcnt[p >> 17], 1);
        ecolS[pos] = p & 0x1FFFF;
    }
}

// ---- stage premultiplied concat: fb[row] = scale[row] * [A;B][row] ----
__global__ void k_stage(const float* __restrict__ A, const float* __restrict__ Bf,
                        const float* __restrict__ scale, int nA, int n,
                        float4* __restrict__ fb) {
    int t = blockIdx.x * blockDim.x + threadIdx.x;   // over n * 16
    if (t >= n * 16) return;
    int row = t >> 4, c4 = t & 15;
    float s = scale[row];
    float4 v = (row < nA) ? ((const float4*)A)[(size_t)row * 16 + c4]
                          : ((const float4*)Bf)[(size_t)(row - nA) * 16 + c4];
    v.x *= s; v.y *= s; v.z *= s; v.w *= s;
    fb[t] = v;
}

// ---- fused CSR-SpMM + scale + l2norm + acc ----
// x is the PREMULTIPLIED staged buffer (x[c] = s[c]*feat[c]); inner loop is
// pure gather-add: 1 shfl + 1 addr + 1 load + 1 add per edge.
// Epilogue: y = acc*s[row]*inv; optional premultiplied write for next layer
// (fout = s[row]*y); l2norm via shfl; acc init (= x[row]/s[row] + r) or +=.
__global__ void k_layer(const int* __restrict__ rowstart, const int* __restrict__ ecol,
                        const float* __restrict__ scale, int n,
                        const float* __restrict__ x, float inv,
                        float* __restrict__ fout, int write_f, int init,
                        float* __restrict__ accA, float* __restrict__ accB) {
    int row = (blockIdx.x << 2) + (threadIdx.x >> 6);
    if (row >= n) return;
    int lane = threadIdx.x & 63;
    int s = rowstart[row], e = rowstart[row + 1];
    float acc = 0.f;
    for (int base = s; base < e; base += 64) {
        int jn = e - base; if (jn > 64) jn = 64;
        int li = base + (lane < jn ? lane : jn - 1);   // clamped vector load
        int cj = ecol[li];
        for (int j = 0; j < jn; j++) {
            int c = __shfl(cj, j, 64);
            acc += x[(size_t)c * D + lane];
        }
    }
    float srow = scale[row];
    float v = acc * srow * inv;
    if (write_f) fout[(size_t)row * D + lane] = v * srow;   // premult for next layer
    float sq = v * v;
    #pragma unroll
    for (int off = 32; off; off >>= 1) sq += __shfl_xor(sq, off, 64);
    float r = v / fmaxf(sqrtf(sq), 1e-12f);
    float* p = (row < U_) ? &accA[(size_t)row * D + lane]
                          : &accB[(size_t)(row - U_) * D + lane];
    if (init) *p = x[(size_t)row * D + lane] / srow + r;    // recover raw feature
    else      *p += r;
}

// Plain CSR-SpMM with row scaling (bundle aggregation): y[r] = rs[r]*sum x[c]
__global__ void k_spmm_csr(const int* __restrict__ rowstart, const int* __restrict__ ecol,
                           const float* __restrict__ rs, int n,
                           const float* __restrict__ x, float* __restrict__ y) {
    int row = (blockIdx.x << 2) + (threadIdx.x >> 6);
    if (row >= n) return;
    int lane = threadIdx.x & 63;
    int s = rowstart[row], e = rowstart[row + 1];
    float acc = 0.f;
    for (int base = s; base < e; base += 64) {
        int jn = e - base; if (jn > 64) jn = 64;
        int li = base + (lane < jn ? lane : jn - 1);
        int cj = ecol[li];
        for (int j = 0; j < jn; j++) {
            int c = __shfl(cj, j, 64);
            acc += x[(size_t)c * D + lane];
        }
    }
    y[(size_t)row * D + lane] = acc * rs[row];
}

extern "C" void kernel_launch(void* const* d_in, const int* in_sizes, int n_in,
                              void* d_out, int out_size, void* d_ws, size_t ws_size,
                              hipStream_t stream) {
    const float* users   = (const float*)d_in[0];
    const float* bundles = (const float*)d_in[1];
    const float* items   = (const float*)d_in[2];
    const int*   ui_idx  = (const int*)d_in[3];
    const int*   ub_idx  = (const int*)d_in[5];
    const int*   ubx_idx = (const int*)d_in[7];
    const int*   agg_idx = (const int*)d_in[9];
    const int ui_nnz  = in_sizes[4];
    const int ub_nnz  = in_sizes[6];
    const int ubx_nnz = in_sizes[8];
    const int agg_nnz = in_sizes[10];

    float* out = (float*)d_out;
    const size_t rowf = (size_t)D;

    // ---- workspace carve-up ----
    const size_t NMAX   = (size_t)(U_ + I_) * D;      // 5.76M floats
    const int    NNZMAX = 2000000;                    // ui graph (largest)
    const int    NROWMX = U_ + I_ + 1;
    float* fbuf    = (float*)d_ws;                    // 23.04 MB staged input
    float* gbuf    = fbuf + NMAX;                     // 23.04 MB premult layer-0 out
    float* acc_itm = gbuf + NMAX;                     // 10.24 MB
    float* scale   = acc_itm + (size_t)I_ * D;        //  0.36 MB
    int*   ep      = (int*)(scale + NROWMX);          //  8.0 MB bucket-grouped
    int*   ecolS   = ep + NNZMAX;                     //  8.0 MB row-sorted cols
    int*   rowstart= ecolS + NNZMAX;                  //  0.36 MB
    int*   bcnt    = rowstart + NROWMX;               //  ~3 KB
    int*   bktbase = bcnt + MAXB;
    int*   bktcur  = bktbase + MAXB + 1;

    // ---- output layout ----
    float* out_IL_u = out;
    float* out_BL_u = out + (size_t)U_ * rowf;
    float* out_XL_u = out + (size_t)2 * U_ * rowf;
    float* out_IL_b = out + (size_t)3 * U_ * rowf;
    float* out_BL_b = out + (size_t)3 * U_ * rowf + (size_t)B_ * rowf;
    float* out_XL_b = out + (size_t)3 * U_ * rowf + (size_t)2 * B_ * rowf;

    auto build = [&](const int* idxp, int nnz, int n, int mode) {
        int nbuck = (n + RPB - 1) / RPB;
        int G = (nnz + TILE - 1) / TILE;
        hipMemsetAsync(bcnt, 0, (size_t)nbuck * sizeof(int), stream);
        hipLaunchKernelGGL(k_histb, dim3(G), dim3(256), 0, stream,
                           idxp, nnz, bcnt, nbuck);
        hipLaunchKernelGGL(k_bscan, dim3(1), dim3(1024), 0, stream,
                           bcnt, nbuck, bktbase, bktcur);
        hipLaunchKernelGGL(k_part, dim3(G), dim3(256), 0, stream,
                           idxp, idxp + nnz, nnz, nbuck, bktcur, ep);
        hipLaunchKernelGGL(k_sort, dim3(nbuck), dim3(256), 0, stream,
                           ep, bktbase, n, mode, ecolS, rowstart, scale);
    };

    auto propagate = [&](const int* idxp, int nnz,
                         const float* Bfeat, int nB, float* accA, float* accB) {
        const int n = U_ + nB;
        build(idxp, nnz, n, 0);
        // stage premultiplied layer-0 input
        hipLaunchKernelGGL(k_stage, dim3((n * 16 + 255) / 256), dim3(256), 0, stream,
                           users, Bfeat, scale, U_, n, (float4*)fbuf);
        // layer 0: y0 = s.*spmm/2 ; acc = raw + l2norm(y0); gbuf = s.*y0
        hipLaunchKernelGGL(k_layer, dim3((n + 3) / 4), dim3(256), 0, stream,
                           rowstart, ecolS, scale, n, fbuf,
                           0.5f, gbuf, 1, 1, accA, accB);
        // layer 1: y1 = s.*spmm(gbuf)/3 ; acc += l2norm(y1); no carry write
        hipLaunchKernelGGL(k_layer, dim3((n + 3) / 4), dim3(256), 0, stream,
                           rowstart, ecolS, scale, n, gbuf,
                           1.0f / 3.0f, (float*)nullptr, 0, 0, accA, accB);
    };

    // item-level propagation over user-item graph
    propagate(ui_idx, ui_nnz, items, I_, out_IL_u, acc_itm);

    // bundle aggregation: IL_b = agg @ IL_i   (row-normalized, raw x)
    build(agg_idx, agg_nnz, B_, 1);
    hipLaunchKernelGGL(k_spmm_csr, dim3((B_ + 3) / 4), dim3(256), 0, stream,
                       rowstart, ecolS, scale, B_, acc_itm, out_IL_b);

    // bundle-level propagation over user-bundle graph
    propagate(ub_idx, ub_nnz, bundles, B_, out_BL_u, out_BL_b);

    // ingredient-augmented user-bundle propagation
    propagate(ubx_idx, ubx_nnz, bundles, B_, out_XL_u, out_XL_b);
}

// Round 8
// 750.569 us; speedup vs baseline: 7.5133x; 1.3815x over previous
//
#include <hip/hip_runtime.h>

#define D 64
constexpr int U_ = 50000, B_ = 20000, I_ = 40000;
constexpr int RPB  = 128;        // rows per bucket
constexpr int MAXB = 708;        // max buckets (n<=90000 -> 704)
constexpr int TILE = 8192;       // edges per partition block

// ---- bucket histogram (LDS-aggregated; no random global atomics) ----
__global__ void k_histb(const int* __restrict__ rows, int nnz,
                        int* __restrict__ bcnt, int nbuck) {
    __shared__ int lb[MAXB];
    for (int i = threadIdx.x; i < nbuck; i += 256) lb[i] = 0;
    __syncthreads();
    int e0 = blockIdx.x * TILE, e1 = min(e0 + TILE, nnz);
    for (int e = e0 + threadIdx.x; e < e1; e += 256)
        atomicAdd(&lb[rows[e] >> 7], 1);
    __syncthreads();
    for (int i = threadIdx.x; i < nbuck; i += 256)
        if (lb[i]) atomicAdd(&bcnt[i], lb[i]);
}

// ---- bucket-count exclusive scan (<=704 entries, one block) ----
__global__ void k_bscan(const int* __restrict__ bcnt, int nbuck,
                        int* __restrict__ bktbase, int* __restrict__ bktcur) {
    __shared__ int sm[1024];
    int t = threadIdx.x;
    sm[t] = (t < nbuck) ? bcnt[t] : 0;
    __syncthreads();
    for (int off = 1; off < 1024; off <<= 1) {
        int v = (t >= off) ? sm[t - off] : 0;
        __syncthreads();
        sm[t] += v;
        __syncthreads();
    }
    if (t < nbuck) { int ex = t ? sm[t - 1] : 0; bktbase[t] = ex; bktcur[t] = ex; }
    if (t == 0) bktbase[nbuck] = sm[1023];
}

// ---- partition edges into bucket-grouped order (packed 4B entries) ----
__global__ void __launch_bounds__(256)
k_part(const int* __restrict__ rows, const int* __restrict__ cols,
       int nnz, int nbuck, int* __restrict__ bktcur, int* __restrict__ ep) {
    __shared__ int lcnt[MAXB], lbase[MAXB];
    int t = threadIdx.x;
    for (int i = t; i < nbuck; i += 256) lcnt[i] = 0;
    __syncthreads();
    int e0 = blockIdx.x * TILE, e1 = min(e0 + TILE, nnz);
    for (int e = e0 + t; e < e1; e += 256)
        atomicAdd(&lcnt[rows[e] >> 7], 1);
    __syncthreads();
    for (int b = t; b < nbuck; b += 256) {
        int c = lcnt[b];
        lbase[b] = c ? atomicAdd(&bktcur[b], c) : 0;
        lcnt[b] = 0;
    }
    __syncthreads();
    for (int e = e0 + t; e < e1; e += 256) {
        int r = rows[e], c = cols[e];
        int b = r >> 7;
        int pos = lbase[b] + atomicAdd(&lcnt[b], 1);
        ep[pos] = ((r & (RPB - 1)) << 17) | c;    // col < 2^17
    }
}

// ---- per-bucket counting sort -> row-exact CSR; emits rowstart & scale ----
__global__ void __launch_bounds__(256)
k_sort(const int* __restrict__ ep, const int* __restrict__ bktbase,
       int n, int mode, int* __restrict__ ecolS,
       int* __restrict__ rowstart, float* __restrict__ scale) {
    __shared__ int lcnt[RPB], lpre[RPB];
    int t = threadIdx.x;
    if (t < RPB) lcnt[t] = 0;
    __syncthreads();
    int s = bktbase[blockIdx.x], e = bktbase[blockIdx.x + 1];
    for (int i = s + t; i < e; i += 256)
        atomicAdd(&lcnt[ep[i] >> 17], 1);
    __syncthreads();
    if (t < RPB) lpre[t] = lcnt[t];
    __syncthreads();
    for (int off = 1; off < RPB; off <<= 1) {      // Hillis-Steele inclusive
        int v = 0;
        if (t < RPB && t >= off) v = lpre[t - off];
        __syncthreads();
        if (t < RPB) lpre[t] += v;
        __syncthreads();
    }
    int r0 = blockIdx.x * RPB;
    if (t < RPB) {
        int row = r0 + t;
        if (row < n) {
            int ex = t ? lpre[t - 1] : 0;
            rowstart[row] = s + ex;
            int c = lcnt[t];
            scale[row] = (mode == 0) ? 1.0f / (sqrtf((float)c) + 1e-8f)
                                     : 1.0f / (float)max(c, 1);
            lcnt[t] = s + ex;                      // reuse as write cursor
        } else lcnt[t] = 0;
    }
    if (blockIdx.x == gridDim.x - 1 && t == 0) rowstart[n] = e;
    __syncthreads();
    for (int i = s + t; i < e; i += 256) {
        int p = ep[i];
        int pos = atomicAdd(&lcnt[p >> 17], 1);
        ecolS[pos] = p & 0x1FFFF;
    }
}

// ---- stage premultiplied concat: fb[row] = scale[row] * [A;B][row] ----
__global__ void k_stage(const float* __restrict__ A, const float* __restrict__ Bf,
                        const float* __restrict__ scale, int nA, int n,
                        float4* __restrict__ fb) {
    int t = blockIdx.x * blockDim.x + threadIdx.x;   // over n * 16
    if (t >= n * 16) return;
    int row = t >> 4, c4 = t & 15;
    float s = scale[row];
    float4 v = (row < nA) ? ((const float4*)A)[(size_t)row * 16 + c4]
                          : ((const float4*)Bf)[(size_t)(row - nA) * 16 + c4];
    v.x *= s; v.y *= s; v.z *= s; v.w *= s;
    fb[t] = v;
}

// ---- fused CSR-SpMM + scale + l2norm + acc ----
// x is PREMULTIPLIED (x[c] = s[c]*feat[c]). Inner loop unrolled x8: issue 8
// broadcast shfls, 8 independent gathers (8 loads in flight), tree-sum.
__global__ void k_layer(const int* __restrict__ rowstart, const int* __restrict__ ecol,
                        const float* __restrict__ scale, int n,
                        const float* __restrict__ x, float inv,
                        float* __restrict__ fout, int write_f, int init,
                        float* __restrict__ accA, float* __restrict__ accB) {
    int row = (blockIdx.x << 2) + (threadIdx.x >> 6);
    if (row >= n) return;
    int lane = threadIdx.x & 63;
    int s = rowstart[row], e = rowstart[row + 1];
    float acc = 0.f;
    for (int base = s; base < e; base += 64) {
        int jn = e - base; if (jn > 64) jn = 64;
        int li = base + (lane < jn ? lane : jn - 1);   // clamped vector load
        int cj = ecol[li];
        int j = 0;
        for (; j + 8 <= jn; j += 8) {
            int c0 = __shfl(cj, j + 0, 64), c1 = __shfl(cj, j + 1, 64);
            int c2 = __shfl(cj, j + 2, 64), c3 = __shfl(cj, j + 3, 64);
            int c4 = __shfl(cj, j + 4, 64), c5 = __shfl(cj, j + 5, 64);
            int c6 = __shfl(cj, j + 6, 64), c7 = __shfl(cj, j + 7, 64);
            float v0 = x[(size_t)c0 * D + lane], v1 = x[(size_t)c1 * D + lane];
            float v2 = x[(size_t)c2 * D + lane], v3 = x[(size_t)c3 * D + lane];
            float v4 = x[(size_t)c4 * D + lane], v5 = x[(size_t)c5 * D + lane];
            float v6 = x[(size_t)c6 * D + lane], v7 = x[(size_t)c7 * D + lane];
            acc += ((v0 + v1) + (v2 + v3)) + ((v4 + v5) + (v6 + v7));
        }
        for (; j < jn; j++) {
            int c = __shfl(cj, j, 64);
            acc += x[(size_t)c * D + lane];
        }
    }
    float srow = scale[row];
    float v = acc * srow * inv;
    if (write_f) fout[(size_t)row * D + lane] = v * srow;   // premult for next layer
    float sq = v * v;
    #pragma unroll
    for (int off = 32; off; off >>= 1) sq += __shfl_xor(sq, off, 64);
    float r = v / fmaxf(sqrtf(sq), 1e-12f);
    float* p = (row < U_) ? &accA[(size_t)row * D + lane]
                          : &accB[(size_t)(row - U_) * D + lane];
    if (init) *p = x[(size_t)row * D + lane] / srow + r;    // recover raw feature
    else      *p += r;
}

// Plain CSR-SpMM with row scaling (bundle aggregation): y[r] = rs[r]*sum x[c]
__global__ void k_spmm_csr(const int* __restrict__ rowstart, const int* __restrict__ ecol,
                           const float* __restrict__ rs, int n,
                           const float* __restrict__ x, float* __restrict__ y) {
    int row = (blockIdx.x << 2) + (threadIdx.x >> 6);
    if (row >= n) return;
    int lane = threadIdx.x & 63;
    int s = rowstart[row], e = rowstart[row + 1];
    float acc = 0.f;
    for (int base = s; base < e; base += 64) {
        int jn = e - base; if (jn > 64) jn = 64;
        int li = base + (lane < jn ? lane : jn - 1);
        int cj = ecol[li];
        int j = 0;
        for (; j + 8 <= jn; j += 8) {
            int c0 = __shfl(cj, j + 0, 64), c1 = __shfl(cj, j + 1, 64);
            int c2 = __shfl(cj, j + 2, 64), c3 = __shfl(cj, j + 3, 64);
            int c4 = __shfl(cj, j + 4, 64), c5 = __shfl(cj, j + 5, 64);
            int c6 = __shfl(cj, j + 6, 64), c7 = __shfl(cj, j + 7, 64);
            float v0 = x[(size_t)c0 * D + lane], v1 = x[(size_t)c1 * D + lane];
            float v2 = x[(size_t)c2 * D + lane], v3 = x[(size_t)c3 * D + lane];
            float v4 = x[(size_t)c4 * D + lane], v5 = x[(size_t)c5 * D + lane];
            float v6 = x[(size_t)c6 * D + lane], v7 = x[(size_t)c7 * D + lane];
            acc += ((v0 + v1) + (v2 + v3)) + ((v4 + v5) + (v6 + v7));
        }
        for (; j < jn; j++) {
            int c = __shfl(cj, j, 64);
            acc += x[(size_t)c * D + lane];
        }
    }
    y[(size_t)row * D + lane] = acc * rs[row];
}

extern "C" void kernel_launch(void* const* d_in, const int* in_sizes, int n_in,
                              void* d_out, int out_size, void* d_ws, size_t ws_size,
                              hipStream_t stream) {
    const float* users   = (const float*)d_in[0];
    const float* bundles = (const float*)d_in[1];
    const float* items   = (const float*)d_in[2];
    const int*   ui_idx  = (const int*)d_in[3];
    const int*   ub_idx  = (const int*)d_in[5];
    const int*   ubx_idx = (const int*)d_in[7];
    const int*   agg_idx = (const int*)d_in[9];
    const int ui_nnz  = in_sizes[4];
    const int ub_nnz  = in_sizes[6];
    const int ubx_nnz = in_sizes[8];
    const int agg_nnz = in_sizes[10];

    float* out = (float*)d_out;
    const size_t rowf = (size_t)D;

    // ---- workspace carve-up ----
    const size_t NMAX   = (size_t)(U_ + I_) * D;      // 5.76M floats
    const int    NNZMAX = 2000000;                    // ui graph (largest)
    const int    NROWMX = U_ + I_ + 1;
    float* fbuf    = (float*)d_ws;                    // 23.04 MB staged input
    float* gbuf    = fbuf + NMAX;                     // 23.04 MB premult layer-0 out
    float* acc_itm = gbuf + NMAX;                     // 10.24 MB
    float* scale   = acc_itm + (size_t)I_ * D;        //  0.36 MB
    int*   ep      = (int*)(scale + NROWMX);          //  8.0 MB bucket-grouped
    int*   ecolS   = ep + NNZMAX;                     //  8.0 MB row-sorted cols
    int*   rowstart= ecolS + NNZMAX;                  //  0.36 MB
    int*   bcnt    = rowstart + NROWMX;               //  ~3 KB
    int*   bktbase = bcnt + MAXB;
    int*   bktcur  = bktbase + MAXB + 1;

    // ---- output layout ----
    float* out_IL_u = out;
    float* out_BL_u = out + (size_t)U_ * rowf;
    float* out_XL_u = out + (size_t)2 * U_ * rowf;
    float* out_IL_b = out + (size_t)3 * U_ * rowf;
    float* out_BL_b = out + (size_t)3 * U_ * rowf + (size_t)B_ * rowf;
    float* out_XL_b = out + (size_t)3 * U_ * rowf + (size_t)2 * B_ * rowf;

    auto build = [&](const int* idxp, int nnz, int n, int mode) {
        int nbuck = (n + RPB - 1) / RPB;
        int G = (nnz + TILE - 1) / TILE;
        hipMemsetAsync(bcnt, 0, (size_t)nbuck * sizeof(int), stream);
        hipLaunchKernelGGL(k_histb, dim3(G), dim3(256), 0, stream,
                           idxp, nnz, bcnt, nbuck);
        hipLaunchKernelGGL(k_bscan, dim3(1), dim3(1024), 0, stream,
                           bcnt, nbuck, bktbase, bktcur);
        hipLaunchKernelGGL(k_part, dim3(G), dim3(256), 0, stream,
                           idxp, idxp + nnz, nnz, nbuck, bktcur, ep);
        hipLaunchKernelGGL(k_sort, dim3(nbuck), dim3(256), 0, stream,
                           ep, bktbase, n, mode, ecolS, rowstart, scale);
    };

    auto propagate = [&](const int* idxp, int nnz,
                         const float* Bfeat, int nB, float* accA, float* accB) {
        const int n = U_ + nB;
        build(idxp, nnz, n, 0);
        // stage premultiplied layer-0 input
        hipLaunchKernelGGL(k_stage, dim3((n * 16 + 255) / 256), dim3(256), 0, stream,
                           users, Bfeat, scale, U_, n, (float4*)fbuf);
        // layer 0: y0 = s.*spmm/2 ; acc = raw + l2norm(y0); gbuf = s.*y0
        hipLaunchKernelGGL(k_layer, dim3((n + 3) / 4), dim3(256), 0, stream,
                           rowstart, ecolS, scale, n, fbuf,
                           0.5f, gbuf, 1, 1, accA, accB);
        // layer 1: y1 = s.*spmm(gbuf)/3 ; acc += l2norm(y1); no carry write
        hipLaunchKernelGGL(k_layer, dim3((n + 3) / 4), dim3(256), 0, stream,
                           rowstart, ecolS, scale, n, gbuf,
                           1.0f / 3.0f, (float*)nullptr, 0, 0, accA, accB);
    };

    // item-level propagation over user-item graph
    propagate(ui_idx, ui_nnz, items, I_, out_IL_u, acc_itm);

    // bundle aggregation: IL_b = agg @ IL_i   (row-normalized, raw x)
    build(agg_idx, agg_nnz, B_, 1);
    hipLaunchKernelGGL(k_spmm_csr, dim3((B_ + 3) / 4), dim3(256), 0, stream,
                       rowstart, ecolS, scale, B_, acc_itm, out_IL_b);

    // bundle-level propagation over user-bundle graph
    propagate(ub_idx, ub_nnz, bundles, B_, out_BL_u, out_BL_b);

    // ingredient-augmented user-bundle propagation
    propagate(ubx_idx, ubx_nnz, bundles, B_, out_XL_u, out_XL_b);
}

// Round 9
// 646.036 us; speedup vs baseline: 8.7290x; 1.1618x over previous
//
#include <hip/hip_runtime.h>

#define D 64
constexpr int U_ = 50000, B_ = 20000, I_ = 40000;
constexpr int RPB  = 128;        // rows per bucket
constexpr int MAXB = 708;        // max buckets (n<=90000 -> 704)
constexpr int TILE = 8192;       // edges per partition block

__device__ __forceinline__ unsigned short f2bf(float f) {   // RTN-even
    unsigned int u = __float_as_uint(f);
    return (unsigned short)((u + 0x7FFFu + ((u >> 16) & 1u)) >> 16);
}
__device__ __forceinline__ float bf2f(unsigned short v) {
    return __uint_as_float((unsigned int)v << 16);
}

// ---- bucket histogram (LDS-aggregated; no random global atomics) ----
__global__ void k_histb(const int* __restrict__ rows, int nnz,
                        int* __restrict__ bcnt, int nbuck) {
    __shared__ int lb[MAXB];
    for (int i = threadIdx.x; i < nbuck; i += 256) lb[i] = 0;
    __syncthreads();
    int e0 = blockIdx.x * TILE, e1 = min(e0 + TILE, nnz);
    for (int e = e0 + threadIdx.x; e < e1; e += 256)
        atomicAdd(&lb[rows[e] >> 7], 1);
    __syncthreads();
    for (int i = threadIdx.x; i < nbuck; i += 256)
        if (lb[i]) atomicAdd(&bcnt[i], lb[i]);
}

// ---- bucket-count exclusive scan (<=704 entries, one block) ----
__global__ void k_bscan(const int* __restrict__ bcnt, int nbuck,
                        int* __restrict__ bktbase, int* __restrict__ bktcur) {
    __shared__ int sm[1024];
    int t = threadIdx.x;
    sm[t] = (t < nbuck) ? bcnt[t] : 0;
    __syncthreads();
    for (int off = 1; off < 1024; off <<= 1) {
        int v = (t >= off) ? sm[t - off] : 0;
        __syncthreads();
        sm[t] += v;
        __syncthreads();
    }
    if (t < nbuck) { int ex = t ? sm[t - 1] : 0; bktbase[t] = ex; bktcur[t] = ex; }
    if (t == 0) bktbase[nbuck] = sm[1023];
}

// ---- partition edges into bucket-grouped order (packed 4B entries) ----
__global__ void __launch_bounds__(256)
k_part(const int* __restrict__ rows, const int* __restrict__ cols,
       int nnz, int nbuck, int* __restrict__ bktcur, int* __restrict__ ep) {
    __shared__ int lcnt[MAXB], lbase[MAXB];
    int t = threadIdx.x;
    for (int i = t; i < nbuck; i += 256) lcnt[i] = 0;
    __syncthreads();
    int e0 = blockIdx.x * TILE, e1 = min(e0 + TILE, nnz);
    for (int e = e0 + t; e < e1; e += 256)
        atomicAdd(&lcnt[rows[e] >> 7], 1);
    __syncthreads();
    for (int b = t; b < nbuck; b += 256) {
        int c = lcnt[b];
        lbase[b] = c ? atomicAdd(&bktcur[b], c) : 0;
        lcnt[b] = 0;
    }
    __syncthreads();
    for (int e = e0 + t; e < e1; e += 256) {
        int r = rows[e], c = cols[e];
        int b = r >> 7;
        int pos = lbase[b] + atomicAdd(&lcnt[b], 1);
        ep[pos] = ((r & (RPB - 1)) << 17) | c;    // col < 2^17
    }
}

// ---- per-bucket counting sort -> row-exact CSR; emits rowstart & scale ----
__global__ void __launch_bounds__(256)
k_sort(const int* __restrict__ ep, const int* __restrict__ bktbase,
       int n, int mode, int* __restrict__ ecolS,
       int* __restrict__ rowstart, float* __restrict__ scale) {
    __shared__ int lcnt[RPB], lpre[RPB];
    int t = threadIdx.x;
    if (t < RPB) lcnt[t] = 0;
    __syncthreads();
    int s = bktbase[blockIdx.x], e = bktbase[blockIdx.x + 1];
    for (int i = s + t; i < e; i += 256)
        atomicAdd(&lcnt[ep[i] >> 17], 1);
    __syncthreads();
    if (t < RPB) lpre[t] = lcnt[t];
    __syncthreads();
    for (int off = 1; off < RPB; off <<= 1) {      // Hillis-Steele inclusive
        int v = 0;
        if (t < RPB && t >= off) v = lpre[t - off];
        __syncthreads();
        if (t < RPB) lpre[t] += v;
        __syncthreads();
    }
    int r0 = blockIdx.x * RPB;
    if (t < RPB) {
        int row = r0 + t;
        if (row < n) {
            int ex = t ? lpre[t - 1] : 0;
            rowstart[row] = s + ex;
            int c = lcnt[t];
            scale[row] = (mode == 0) ? 1.0f / (sqrtf((float)c) + 1e-8f)
                                     : 1.0f / (float)max(c, 1);
            lcnt[t] = s + ex;                      // reuse as write cursor
        } else lcnt[t] = 0;
    }
    if (blockIdx.x == gridDim.x - 1 && t == 0) rowstart[n] = e;
    __syncthreads();
    for (int i = s + t; i < e; i += 256) {
        int p = ep[i];
        int pos = atomicAdd(&lcnt[p >> 17], 1);
        ecolS[pos] = p & 0x1FFFF;
    }
}

// ---- stage premultiplied concat as bf16: fb[row] = bf16(s[row]*[A;B][row]) ----
// Row n (= zrow) is zero-filled in BOTH fb and gb (gather redirect target).
__global__ void k_stage(const float* __restrict__ A, const float* __restrict__ Bf,
                        const float* __restrict__ scale, int nA, int n,
                        ushort* __restrict__ fb, ushort* __restrict__ gb) {
    int t = blockIdx.x * blockDim.x + threadIdx.x;   // over (n+1)*16
    if (t >= (n + 1) * 16) return;
    int row = t >> 4, q = t & 15;
    ushort4 o;
    if (row == n) {
        o = make_ushort4(0, 0, 0, 0);
        ((ushort4*)gb)[t] = o;
    } else {
        float s = scale[row];
        float4 v = (row < nA) ? ((const float4*)A)[(size_t)row * 16 + q]
                              : ((const float4*)Bf)[(size_t)(row - nA) * 16 + q];
        o.x = f2bf(v.x * s); o.y = f2bf(v.y * s);
        o.z = f2bf(v.z * s); o.w = f2bf(v.w * s);
    }
    ((ushort4*)fb)[t] = o;
}

// ---- fused CSR-SpMM + scale + l2norm + acc (bf16 quad-row gather) ----
// Wave = 1 row; 4 groups of 16 lanes each gather a different edge's row
// via ushort4 (8B) loads: 4 edges per load instruction, 2 loads in flight.
// x premultiplied bf16. Epilogue: cross-group reduce, scale, l2norm, acc.
__global__ void __launch_bounds__(256)
k_layer(const int* __restrict__ rowstart, const int* __restrict__ ecol,
        const float* __restrict__ scale, int n, int zrow,
        const ushort* __restrict__ x, float inv,
        const float* __restrict__ rawA, const float* __restrict__ rawB_adj,
        ushort* __restrict__ fout, int write_f, int init,
        float* __restrict__ accA, float* __restrict__ accB) {
    int row = (blockIdx.x << 2) + (threadIdx.x >> 6);
    if (row >= n) return;
    int lane = threadIdx.x & 63;
    int g = lane >> 4, q = lane & 15;
    int s = rowstart[row], e = rowstart[row + 1];
    float ax = 0.f, ay = 0.f, az = 0.f, aw = 0.f;
    for (int base = s; base < e; base += 64) {
        int jn = e - base; if (jn > 64) jn = 64;
        int li = base + (lane < jn ? lane : jn - 1);   // clamped vector load
        int cj = ecol[li];
        for (int j4 = 0; j4 < jn; j4 += 8) {
            int jj0 = j4 + g, jj1 = j4 + 4 + g;
            int c0 = __shfl(cj, jj0 < jn ? jj0 : 0, 64);
            int c1 = __shfl(cj, jj1 < jn ? jj1 : 0, 64);
            if (jj0 >= jn) c0 = zrow;                  // zero-row redirect
            if (jj1 >= jn) c1 = zrow;
            ushort4 u0 = *(const ushort4*)(x + ((size_t)c0 << 6) + (q << 2));
            ushort4 u1 = *(const ushort4*)(x + ((size_t)c1 << 6) + (q << 2));
            ax += bf2f(u0.x) + bf2f(u1.x);
            ay += bf2f(u0.y) + bf2f(u1.y);
            az += bf2f(u0.z) + bf2f(u1.z);
            aw += bf2f(u0.w) + bf2f(u1.w);
        }
    }
    // cross-group reduction (groups hold disjoint edge subsets)
    ax += __shfl_xor(ax, 16, 64); ax += __shfl_xor(ax, 32, 64);
    ay += __shfl_xor(ay, 16, 64); ay += __shfl_xor(ay, 32, 64);
    az += __shfl_xor(az, 16, 64); az += __shfl_xor(az, 32, 64);
    aw += __shfl_xor(aw, 16, 64); aw += __shfl_xor(aw, 32, 64);
    float srow = scale[row];
    float m = srow * inv;
    float vx = ax * m, vy = ay * m, vz = az * m, vw = aw * m;
    float sq = vx * vx + vy * vy + vz * vz + vw * vw;   // 16 lanes cover 64 dims
    sq += __shfl_xor(sq, 1, 64); sq += __shfl_xor(sq, 2, 64);
    sq += __shfl_xor(sq, 4, 64); sq += __shfl_xor(sq, 8, 64);
    float rn = 1.0f / fmaxf(sqrtf(sq), 1e-12f);
    if (g == 0) {                                      // lanes 0-15 own the row
        size_t o = ((size_t)row << 6) + (q << 2);
        if (write_f) {
            ushort4 ob;
            ob.x = f2bf(vx * srow); ob.y = f2bf(vy * srow);
            ob.z = f2bf(vz * srow); ob.w = f2bf(vw * srow);
            *(ushort4*)(fout + o) = ob;                // premult for next layer
        }
        float4 r4 = make_float4(vx * rn, vy * rn, vz * rn, vw * rn);
        float* p = (row < U_) ? accA + o : accB + (o - ((size_t)U_ << 6));
        float4 ov;
        if (init) {
            float4 raw = (row < U_) ? ((const float4*)rawA)[(size_t)row * 16 + q]
                                    : ((const float4*)rawB_adj)[(size_t)row * 16 + q];
            ov = make_float4(raw.x + r4.x, raw.y + r4.y, raw.z + r4.z, raw.w + r4.w);
        } else {
            float4 cur = *(const float4*)p;
            ov = make_float4(cur.x + r4.x, cur.y + r4.y, cur.z + r4.z, cur.w + r4.w);
        }
        *(float4*)p = ov;
    }
}

// Plain fp32 CSR-SpMM with row scaling (bundle aggregation, small)
__global__ void k_spmm_csr(const int* __restrict__ rowstart, const int* __restrict__ ecol,
                           const float* __restrict__ rs, int n,
                           const float* __restrict__ x, float* __restrict__ y) {
    int row = (blockIdx.x << 2) + (threadIdx.x >> 6);
    if (row >= n) return;
    int lane = threadIdx.x & 63;
    int s = rowstart[row], e = rowstart[row + 1];
    float acc = 0.f;
    for (int base = s; base < e; base += 64) {
        int jn = e - base; if (jn > 64) jn = 64;
        int li = base + (lane < jn ? lane : jn - 1);
        int cj = ecol[li];
        int j = 0;
        for (; j + 8 <= jn; j += 8) {
            int c0 = __shfl(cj, j + 0, 64), c1 = __shfl(cj, j + 1, 64);
            int c2 = __shfl(cj, j + 2, 64), c3 = __shfl(cj, j + 3, 64);
            int c4 = __shfl(cj, j + 4, 64), c5 = __shfl(cj, j + 5, 64);
            int c6 = __shfl(cj, j + 6, 64), c7 = __shfl(cj, j + 7, 64);
            float v0 = x[(size_t)c0 * D + lane], v1 = x[(size_t)c1 * D + lane];
            float v2 = x[(size_t)c2 * D + lane], v3 = x[(size_t)c3 * D + lane];
            float v4 = x[(size_t)c4 * D + lane], v5 = x[(size_t)c5 * D + lane];
            float v6 = x[(size_t)c6 * D + lane], v7 = x[(size_t)c7 * D + lane];
            acc += ((v0 + v1) + (v2 + v3)) + ((v4 + v5) + (v6 + v7));
        }
        for (; j < jn; j++) {
            int c = __shfl(cj, j, 64);
            acc += x[(size_t)c * D + lane];
        }
    }
    y[(size_t)row * D + lane] = acc * rs[row];
}

extern "C" void kernel_launch(void* const* d_in, const int* in_sizes, int n_in,
                              void* d_out, int out_size, void* d_ws, size_t ws_size,
                              hipStream_t stream) {
    const float* users   = (const float*)d_in[0];
    const float* bundles = (const float*)d_in[1];
    const float* items   = (const float*)d_in[2];
    const int*   ui_idx  = (const int*)d_in[3];
    const int*   ub_idx  = (const int*)d_in[5];
    const int*   ubx_idx = (const int*)d_in[7];
    const int*   agg_idx = (const int*)d_in[9];
    const int ui_nnz  = in_sizes[4];
    const int ub_nnz  = in_sizes[6];
    const int ubx_nnz = in_sizes[8];
    const int agg_nnz = in_sizes[10];

    float* out = (float*)d_out;
    const size_t rowf = (size_t)D;

    // ---- workspace carve-up ----
    const int    NNZMAX = 2000000;                    // ui graph (largest)
    const int    NROWMX = U_ + I_ + 1;                // 90001 (incl zero row)
    ushort* fb16   = (ushort*)d_ws;                   // 11.52 MB staged bf16
    ushort* gb16   = fb16 + (size_t)NROWMX * D;       // 11.52 MB premult layer-0 out
    float* acc_itm = (float*)(gb16 + (size_t)NROWMX * D);   // 10.24 MB
    float* scale   = acc_itm + (size_t)I_ * D;        //  0.36 MB
    int*   ep      = (int*)(scale + NROWMX);          //  8.0 MB bucket-grouped
    int*   ecolS   = ep + NNZMAX;                     //  8.0 MB row-sorted cols
    int*   rowstart= ecolS + NNZMAX;                  //  0.36 MB
    int*   bcnt    = rowstart + NROWMX;               //  ~3 KB
    int*   bktbase = bcnt + MAXB;
    int*   bktcur  = bktbase + MAXB + 1;

    // ---- output layout ----
    float* out_IL_u = out;
    float* out_BL_u = out + (size_t)U_ * rowf;
    float* out_XL_u = out + (size_t)2 * U_ * rowf;
    float* out_IL_b = out + (size_t)3 * U_ * rowf;
    float* out_BL_b = out + (size_t)3 * U_ * rowf + (size_t)B_ * rowf;
    float* out_XL_b = out + (size_t)3 * U_ * rowf + (size_t)2 * B_ * rowf;

    auto build = [&](const int* idxp, int nnz, int n, int mode) {
        int nbuck = (n + RPB - 1) / RPB;
        int G = (nnz + TILE - 1) / TILE;
        hipMemsetAsync(bcnt, 0, (size_t)nbuck * sizeof(int), stream);
        hipLaunchKernelGGL(k_histb, dim3(G), dim3(256), 0, stream,
                           idxp, nnz, bcnt, nbuck);
        hipLaunchKernelGGL(k_bscan, dim3(1), dim3(1024), 0, stream,
                           bcnt, nbuck, bktbase, bktcur);
        hipLaunchKernelGGL(k_part, dim3(G), dim3(256), 0, stream,
                           idxp, idxp + nnz, nnz, nbuck, bktcur, ep);
        hipLaunchKernelGGL(k_sort, dim3(nbuck), dim3(256), 0, stream,
                           ep, bktbase, n, mode, ecolS, rowstart, scale);
    };

    auto propagate = [&](const int* idxp, int nnz,
                         const float* Bfeat, int nB, float* accA, float* accB) {
        const int n = U_ + nB;
        build(idxp, nnz, n, 0);
        // stage premultiplied bf16 layer-0 input (+ zero row n in fb & gb)
        hipLaunchKernelGGL(k_stage, dim3(((n + 1) * 16 + 255) / 256), dim3(256),
                           0, stream, users, Bfeat, scale, U_, n, fb16, gb16);
        // layer 0: y0 = s.*spmm/2 ; acc = raw + l2norm(y0); gb16 = bf16(s.*y0)
        hipLaunchKernelGGL(k_layer, dim3((n + 3) / 4), dim3(256), 0, stream,
                           rowstart, ecolS, scale, n, n, fb16, 0.5f,
                           users, bundles ? (Bfeat - (size_t)U_ * rowf) : nullptr,
                           gb16, 1, 1, accA, accB);
        // layer 1: y1 = s.*spmm(gb16)/3 ; acc += l2norm(y1)
        hipLaunchKernelGGL(k_layer, dim3((n + 3) / 4), dim3(256), 0, stream,
                           rowstart, ecolS, scale, n, n, gb16, 1.0f / 3.0f,
                           users, Bfeat - (size_t)U_ * rowf,
                           (ushort*)nullptr, 0, 0, accA, accB);
    };

    // item-level propagation over user-item graph
    propagate(ui_idx, ui_nnz, items, I_, out_IL_u, acc_itm);

    // bundle aggregation: IL_b = agg @ IL_i   (row-normalized, fp32 path)
    build(agg_idx, agg_nnz, B_, 1);
    hipLaunchKernelGGL(k_spmm_csr, dim3((B_ + 3) / 4), dim3(256), 0, stream,
                       rowstart, ecolS, scale, B_, acc_itm, out_IL_b);

    // bundle-level propagation over user-bundle graph
    propagate(ub_idx, ub_nnz, bundles, B_, out_BL_u, out_BL_b);

    // ingredient-augmented user-bundle propagation
    propagate(ubx_idx, ubx_nnz, bundles, B_, out_XL_u, out_XL_b);
}

// Round 10
// 628.437 us; speedup vs baseline: 8.9734x; 1.0280x over previous
//
#include <hip/hip_runtime.h>

#define D 64
constexpr int U_ = 50000, B_ = 20000, I_ = 40000;
constexpr int RPB  = 128;        // rows per bucket
constexpr int MAXB = 708;        // max buckets (n<=90000 -> 704)
constexpr int TILE = 8192;       // edges per partition block

__device__ __forceinline__ unsigned short f2bf(float f) {   // RTN-even
    unsigned int u = __float_as_uint(f);
    return (unsigned short)((u + 0x7FFFu + ((u >> 16) & 1u)) >> 16);
}
__device__ __forceinline__ float bf2f(unsigned short v) {
    return __uint_as_float((unsigned int)v << 16);
}

// ---- init per-bucket global cursors to fixed-capacity bases ----
__global__ void k_binit(int* __restrict__ bktcur, int nbuck, int cap) {
    int i = blockIdx.x * blockDim.x + threadIdx.x;
    if (i < nbuck) bktcur[i] = i * cap;
}

// ---- partition edges into fixed-capacity bucket regions (packed 4B) ----
// No pre-count pass needed: blocks reserve space via global per-bucket atomics.
__global__ void __launch_bounds__(256)
k_part(const int* __restrict__ rows, const int* __restrict__ cols,
       int nnz, int nbuck, int cap, int* __restrict__ bktcur, int* __restrict__ ep) {
    __shared__ int lcnt[MAXB], lbase[MAXB];
    int t = threadIdx.x;
    for (int i = t; i < nbuck; i += 256) lcnt[i] = 0;
    __syncthreads();
    int e0 = blockIdx.x * TILE, e1 = min(e0 + TILE, nnz);
    for (int e = e0 + t; e < e1; e += 256)
        atomicAdd(&lcnt[rows[e] >> 7], 1);
    __syncthreads();
    for (int b = t; b < nbuck; b += 256) {
        int c = lcnt[b];
        lbase[b] = c ? atomicAdd(&bktcur[b], c) : 0;
        lcnt[b] = 0;
    }
    __syncthreads();
    for (int e = e0 + t; e < e1; e += 256) {
        int r = rows[e], c = cols[e];
        int b = r >> 7;
        int pos = lbase[b] + atomicAdd(&lcnt[b], 1);
        if (pos < (b + 1) * cap)                     // overflow guard (>=9 sigma)
            ep[pos] = ((r & (RPB - 1)) << 17) | c;   // col < 2^17
    }
}

// ---- per-bucket counting sort -> row-exact CSR + scale + FUSED bf16 stage ----
__global__ void __launch_bounds__(256)
k_sort(const int* __restrict__ ep, const int* __restrict__ bktcur, int cap,
       int n, int mode, int* __restrict__ ecolS,
       int* __restrict__ rowstart, int* __restrict__ rowend,
       float* __restrict__ scale, int do_stage,
       const float* __restrict__ rawA, const float* __restrict__ rawB_adj,
       ushort* __restrict__ fb) {
    __shared__ int lcnt[RPB], lpre[RPB];
    __shared__ float sscale[RPB];
    int t = threadIdx.x;
    int b = blockIdx.x;
    int s = b * cap;
    int e = min(bktcur[b], s + cap);
    if (t < RPB) lcnt[t] = 0;
    __syncthreads();
    for (int i = s + t; i < e; i += 256)
        atomicAdd(&lcnt[ep[i] >> 17], 1);
    __syncthreads();
    if (t < RPB) lpre[t] = lcnt[t];
    __syncthreads();
    for (int off = 1; off < RPB; off <<= 1) {      // Hillis-Steele inclusive
        int v = 0;
        if (t < RPB && t >= off) v = lpre[t - off];
        __syncthreads();
        if (t < RPB) lpre[t] += v;
        __syncthreads();
    }
    int r0 = b * RPB;
    if (t < RPB) {
        int row = r0 + t;
        if (row < n) {
            int ex = t ? lpre[t - 1] : 0;
            int c = lcnt[t];
            rowstart[row] = s + ex;
            rowend[row]   = s + ex + c;
            float sc = (mode == 0) ? 1.0f / (sqrtf((float)c) + 1e-8f)
                                   : 1.0f / (float)max(c, 1);
            scale[row] = sc;
            sscale[t] = sc;
            lcnt[t] = s + ex;                      // reuse as write cursor
        } else lcnt[t] = 0;
    }
    __syncthreads();
    for (int i = s + t; i < e; i += 256) {
        int p = ep[i];
        int pos = atomicAdd(&lcnt[p >> 17], 1);
        ecolS[pos] = p & 0x1FFFF;
    }
    if (do_stage) {                                // fused premultiplied bf16 stage
        for (int idx = t; idx < RPB * 16; idx += 256) {
            int rl = idx >> 4, q = idx & 15;
            int row = r0 + rl;
            if (row > n) continue;
            ushort4 o;
            if (row == n) {
                o = make_ushort4(0, 0, 0, 0);      // zero redirect row
            } else {
                float sc = sscale[rl];
                float4 v = (row < U_) ? ((const float4*)rawA)[(size_t)row * 16 + q]
                                      : ((const float4*)rawB_adj)[(size_t)row * 16 + q];
                o.x = f2bf(v.x * sc); o.y = f2bf(v.y * sc);
                o.z = f2bf(v.z * sc); o.w = f2bf(v.w * sc);
            }
            ((ushort4*)fb)[(size_t)row * 16 + q] = o;
        }
    }
}

// ---- zero the redirect row of the (ep-aliased) layer-0 output buffer ----
__global__ void k_zrow(ushort* __restrict__ gb, int n) {
    ((ushort4*)(gb + ((size_t)n << 6)))[threadIdx.x] = make_ushort4(0, 0, 0, 0);
}

// ---- fused CSR-SpMM + scale + l2norm + acc (bf16 quad-row gather) ----
// Unchanged round-9 structure; row extent now rowstart[]/rowend[].
__global__ void __launch_bounds__(256)
k_layer(const int* __restrict__ rowstart, const int* __restrict__ rowend,
        const int* __restrict__ ecol,
        const float* __restrict__ scale, int n, int zrow,
        const ushort* __restrict__ x, float inv,
        const float* __restrict__ rawA, const float* __restrict__ rawB_adj,
        ushort* __restrict__ fout, int write_f, int init,
        float* __restrict__ accA, float* __restrict__ accB) {
    int row = (blockIdx.x << 2) + (threadIdx.x >> 6);
    if (row >= n) return;
    int lane = threadIdx.x & 63;
    int g = lane >> 4, q = lane & 15;
    int s = rowstart[row], e = rowend[row];
    float ax = 0.f, ay = 0.f, az = 0.f, aw = 0.f;
    for (int base = s; base < e; base += 64) {
        int jn = e - base; if (jn > 64) jn = 64;
        int li = base + (lane < jn ? lane : jn - 1);   // clamped vector load
        int cj = ecol[li];
        for (int j4 = 0; j4 < jn; j4 += 8) {
            int jj0 = j4 + g, jj1 = j4 + 4 + g;
            int c0 = __shfl(cj, jj0 < jn ? jj0 : 0, 64);
            int c1 = __shfl(cj, jj1 < jn ? jj1 : 0, 64);
            if (jj0 >= jn) c0 = zrow;                  // zero-row redirect
            if (jj1 >= jn) c1 = zrow;
            ushort4 u0 = *(const ushort4*)(x + ((size_t)c0 << 6) + (q << 2));
            ushort4 u1 = *(const ushort4*)(x + ((size_t)c1 << 6) + (q << 2));
            ax += bf2f(u0.x) + bf2f(u1.x);
            ay += bf2f(u0.y) + bf2f(u1.y);
            az += bf2f(u0.z) + bf2f(u1.z);
            aw += bf2f(u0.w) + bf2f(u1.w);
        }
    }
    // cross-group reduction (groups hold disjoint edge subsets)
    ax += __shfl_xor(ax, 16, 64); ax += __shfl_xor(ax, 32, 64);
    ay += __shfl_xor(ay, 16, 64); ay += __shfl_xor(ay, 32, 64);
    az += __shfl_xor(az, 16, 64); az += __shfl_xor(az, 32, 64);
    aw += __shfl_xor(aw, 16, 64); aw += __shfl_xor(aw, 32, 64);
    float srow = scale[row];
    float m = srow * inv;
    float vx = ax * m, vy = ay * m, vz = az * m, vw = aw * m;
    float sq = vx * vx + vy * vy + vz * vz + vw * vw;   // 16 lanes cover 64 dims
    sq += __shfl_xor(sq, 1, 64); sq += __shfl_xor(sq, 2, 64);
    sq += __shfl_xor(sq, 4, 64); sq += __shfl_xor(sq, 8, 64);
    float rn = 1.0f / fmaxf(sqrtf(sq), 1e-12f);
    if (g == 0) {                                      // lanes 0-15 own the row
        size_t o = ((size_t)row << 6) + (q << 2);
        if (write_f) {
            ushort4 ob;
            ob.x = f2bf(vx * srow); ob.y = f2bf(vy * srow);
            ob.z = f2bf(vz * srow); ob.w = f2bf(vw * srow);
            *(ushort4*)(fout + o) = ob;                // premult for next layer
        }
        float4 r4 = make_float4(vx * rn, vy * rn, vz * rn, vw * rn);
        float* p = (row < U_) ? accA + o : accB + (o - ((size_t)U_ << 6));
        float4 ov;
        if (init) {
            float4 raw = (row < U_) ? ((const float4*)rawA)[(size_t)row * 16 + q]
                                    : ((const float4*)rawB_adj)[(size_t)row * 16 + q];
            ov = make_float4(raw.x + r4.x, raw.y + r4.y, raw.z + r4.z, raw.w + r4.w);
        } else {
            float4 cur = *(const float4*)p;
            ov = make_float4(cur.x + r4.x, cur.y + r4.y, cur.z + r4.z, cur.w + r4.w);
        }
        *(float4*)p = ov;
    }
}

// Plain fp32 CSR-SpMM with row scaling (bundle aggregation, small)
__global__ void k_spmm_csr(const int* __restrict__ rowstart, const int* __restrict__ rowend,
                           const int* __restrict__ ecol,
                           const float* __restrict__ rs, int n,
                           const float* __restrict__ x, float* __restrict__ y) {
    int row = (blockIdx.x << 2) + (threadIdx.x >> 6);
    if (row >= n) return;
    int lane = threadIdx.x & 63;
    int s = rowstart[row], e = rowend[row];
    float acc = 0.f;
    for (int base = s; base < e; base += 64) {
        int jn = e - base; if (jn > 64) jn = 64;
        int li = base + (lane < jn ? lane : jn - 1);
        int cj = ecol[li];
        int j = 0;
        for (; j + 8 <= jn; j += 8) {
            int c0 = __shfl(cj, j + 0, 64), c1 = __shfl(cj, j + 1, 64);
            int c2 = __shfl(cj, j + 2, 64), c3 = __shfl(cj, j + 3, 64);
            int c4 = __shfl(cj, j + 4, 64), c5 = __shfl(cj, j + 5, 64);
            int c6 = __shfl(cj, j + 6, 64), c7 = __shfl(cj, j + 7, 64);
            float v0 = x[(size_t)c0 * D + lane], v1 = x[(size_t)c1 * D + lane];
            float v2 = x[(size_t)c2 * D + lane], v3 = x[(size_t)c3 * D + lane];
            float v4 = x[(size_t)c4 * D + lane], v5 = x[(size_t)c5 * D + lane];
            float v6 = x[(size_t)c6 * D + lane], v7 = x[(size_t)c7 * D + lane];
            acc += ((v0 + v1) + (v2 + v3)) + ((v4 + v5) + (v6 + v7));
        }
        for (; j < jn; j++) {
            int c = __shfl(cj, j, 64);
            acc += x[(size_t)c * D + lane];
        }
    }
    y[(size_t)row * D + lane] = acc * rs[row];
}

extern "C" void kernel_launch(void* const* d_in, const int* in_sizes, int n_in,
                              void* d_out, int out_size, void* d_ws, size_t ws_size,
                              hipStream_t stream) {
    const float* users   = (const float*)d_in[0];
    const float* bundles = (const float*)d_in[1];
    const float* items   = (const float*)d_in[2];
    const int*   ui_idx  = (const int*)d_in[3];
    const int*   ub_idx  = (const int*)d_in[5];
    const int*   ubx_idx = (const int*)d_in[7];
    const int*   agg_idx = (const int*)d_in[9];
    const int ui_nnz  = in_sizes[4];
    const int ub_nnz  = in_sizes[6];
    const int ubx_nnz = in_sizes[8];
    const int agg_nnz = in_sizes[10];

    float* out = (float*)d_out;
    const size_t rowf = (size_t)D;

    // ---- workspace carve-up (~49.7 MB) ----
    const int NROWPAD = 90004;                        // 90001 rows, 16B-align pad
    const int EPMAX   = 547 * 6144;                   // 3,360,768 (ubx worst case)
    ushort* fb16    = (ushort*)d_ws;                  // 11.52 MB staged bf16
    float*  acc_itm = (float*)(fb16 + (size_t)(90001) * D + 32); // align 16B
    float*  scale   = acc_itm + (size_t)I_ * D;       //  0.36 MB
    int*    ep      = (int*)(scale + NROWPAD);        // 13.44 MB bucket regions
    ushort* gb16    = (ushort*)ep;                    // ALIASES ep (dead after sort)
    int*    ecolS   = ep + EPMAX;                     // 13.44 MB row-sorted cols
    int*    rowstart= ecolS + EPMAX;                  //  0.36 MB
    int*    rowend  = rowstart + NROWPAD;             //  0.36 MB
    int*    bktcur  = rowend + NROWPAD;               //  ~3 KB

    // ---- output layout ----
    float* out_IL_u = out;
    float* out_BL_u = out + (size_t)U_ * rowf;
    float* out_XL_u = out + (size_t)2 * U_ * rowf;
    float* out_IL_b = out + (size_t)3 * U_ * rowf;
    float* out_BL_b = out + (size_t)3 * U_ * rowf + (size_t)B_ * rowf;
    float* out_XL_b = out + (size_t)3 * U_ * rowf + (size_t)2 * B_ * rowf;

    auto build = [&](const int* idxp, int nnz, int n, int cap, int mode,
                     int do_stage, const float* A, const float* Badj) {
        int nbuck = (n + RPB - 1) / RPB;
        int G = (nnz + TILE - 1) / TILE;
        hipLaunchKernelGGL(k_binit, dim3((nbuck + 255) / 256), dim3(256), 0, stream,
                           bktcur, nbuck, cap);
        hipLaunchKernelGGL(k_part, dim3(G), dim3(256), 0, stream,
                           idxp, idxp + nnz, nnz, nbuck, cap, bktcur, ep);
        hipLaunchKernelGGL(k_sort, dim3(nbuck), dim3(256), 0, stream,
                           ep, bktcur, cap, n, mode, ecolS, rowstart, rowend,
                           scale, do_stage, A, Badj, fb16);
    };

    auto propagate = [&](const int* idxp, int nnz, int cap,
                         const float* Bfeat, int nB, float* accA, float* accB) {
        const int n = U_ + nB;
        const float* Badj = Bfeat - (size_t)U_ * rowf;
        build(idxp, nnz, n, cap, 0, 1, users, Badj);
        hipLaunchKernelGGL(k_zrow, dim3(1), dim3(16), 0, stream, gb16, n);
        // layer 0: y0 = s.*spmm(fb16)/2 ; acc = raw + l2norm(y0); gb16 = bf16(s.*y0)
        hipLaunchKernelGGL(k_layer, dim3((n + 3) / 4), dim3(256), 0, stream,
                           rowstart, rowend, ecolS, scale, n, n, fb16, 0.5f,
                           users, Badj, gb16, 1, 1, accA, accB);
        // layer 1: y1 = s.*spmm(gb16)/3 ; acc += l2norm(y1)
        hipLaunchKernelGGL(k_layer, dim3((n + 3) / 4), dim3(256), 0, stream,
                           rowstart, rowend, ecolS, scale, n, n, gb16, 1.0f / 3.0f,
                           users, Badj, (ushort*)nullptr, 0, 0, accA, accB);
    };

    // item-level propagation over user-item graph
    propagate(ui_idx, ui_nnz, 4096, items, I_, out_IL_u, acc_itm);

    // bundle aggregation: IL_b = agg @ IL_i   (row-normalized, fp32 path)
    build(agg_idx, agg_nnz, B_, 2560, 1, 0, users, users);
    hipLaunchKernelGGL(k_spmm_csr, dim3((B_ + 3) / 4), dim3(256), 0, stream,
                       rowstart, rowend, ecolS, scale, B_, acc_itm, out_IL_b);

    // bundle-level propagation over user-bundle graph
    propagate(ub_idx, ub_nnz, 4608, bundles, B_, out_BL_u, out_BL_b);

    // ingredient-augmented user-bundle propagation
    propagate(ubx_idx, ubx_nnz, 6144, bundles, B_, out_XL_u, out_XL_b);
}